// Round 1
// baseline (130.049 us; speedup 1.0000x reference)
//
#include <hip/hip_runtime.h>
#include <math.h>

// Problem constants
constexpr int NH    = 778;           // hand verts per batch
constexpr int GRIDC = 16;            // cells per axis (0.1 m cube -> 6.25 mm cells)
constexpr int NCELL = GRIDC * GRIDC * GRIDC;   // 4096
constexpr int CAP   = 40;            // bucket cap (Poisson mean ~9.8; P(>40)~1e-14)
constexpr int CS    = 16;            // cnt stride in ints: 1 cacheline/cell (R12: kill
                                     // atomic line-bouncing; 16 cells shared a line before)
constexpr float CELL     = 0.1f / GRIDC;       // 0.00625
constexpr float INV_CELL = GRIDC / 0.1f;       // 160
constexpr int NSH = 32;              // accumulator shards (cuts same-address atomic depth)

__device__ __forceinline__ int clampc(int v) {
    return min(GRIDC - 1, max(0, v));
}

// ---------------------------------------------------------------------------
// K1: bin obj points into per-(batch,cell) buckets. Overflow (idx >= CAP)
// goes to a global list tagged with batch (capacity = ALL points -> always
// exact for any distribution). Insertion order is atomic-nondeterministic;
// min over the union is order-independent.
// ---------------------------------------------------------------------------
__global__ __launch_bounds__(256) void bin_kernel(
    const float* __restrict__ obj,   // [B, V, 3] flat
    int* __restrict__ cnt,           // [B*NCELL*CS]
    int* __restrict__ ocnt,          // overflow counter
    float4* __restrict__ buckets,    // [B*NCELL*CAP]
    float4* __restrict__ ovf,        // [B*V] worst case
    int total, int V)
{
    const int i = blockIdx.x * 256 + threadIdx.x;
    if (i >= total) return;
    const float x = obj[3 * i + 0];
    const float y = obj[3 * i + 1];
    const float z = obj[3 * i + 2];
    const int cx = clampc((int)(x * INV_CELL));
    const int cy = clampc((int)(y * INV_CELL));
    const int cz = clampc((int)(z * INV_CELL));
    const int b = i / V;
    const int cell = b * NCELL + (cz * GRIDC + cy) * GRIDC + cx;
    const int idx = atomicAdd(&cnt[(size_t)cell * CS], 1);
    if (idx < CAP) {
        buckets[(size_t)cell * CAP + idx] = make_float4(x, y, z, 0.f);
    } else {
        const int oi = atomicAdd(ocnt, 1);   // oi < total always
        ovf[oi] = make_float4(x, y, z, __int_as_float(b));
    }
}

// ---------------------------------------------------------------------------
// K2 (R12: finalize fused in): exact grid NN query, ONE WAVE PER QUERY, then
// per-block stat reduction + sharded device-scope atomics + last-block-ticket
// finalization. Removes the single-block finalize dispatch and its graph
// boundary (~6-10 us latency tail on 1 CU).
// Exactness: h lies inside its own cell, so after completing cube radius r-1
// every unscanned point is >= (r-1)*CELL away; stop iff best <= ((r-1)*CELL)^2.
// ---------------------------------------------------------------------------
__global__ __launch_bounds__(256) void query_fused_kernel(
    const float* __restrict__ hand,    // [B, NH, 3] flat
    const int* __restrict__ cnt,       // [B*NCELL*CS]
    const float4* __restrict__ buckets,// [B*NCELL*CAP]
    const float4* __restrict__ ovf,
    const int* __restrict__ ocnt,
    double* __restrict__ shd,          // [NSH][3] f64 shards: sum_d, pen_sum, att_sum
    int* __restrict__ shi,             // [NSH][2] int shards: pen_cnt, att_cnt
    int* __restrict__ ticket,          // last-block ticket
    float* __restrict__ out,           // 6 outputs
    int nq, int B)
{
    constexpr float COLL = 0.005f;
    constexpr float CONT = 0.01f;
    const int tid  = threadIdx.x;
    const int wave = tid >> 6;
    const int lane = tid & 63;
    const int i    = blockIdx.x * 4 + wave;   // query (hand point) id: 1 wave each
    const bool valid = i < nq;

    float best = 3.4e38f;

    if (valid) {
        const int b = i / NH;
        const float hx = hand[3 * i + 0];
        const float hy = hand[3 * i + 1];
        const float hz = hand[3 * i + 2];
        const int hcx = clampc((int)(hx * INV_CELL));
        const int hcy = clampc((int)(hy * INV_CELL));
        const int hcz = clampc((int)(hz * INV_CELL));
        const int cbase = b * NCELL;

        // phase 1: radius-1 cube (27 cells), 2 lanes per cell (lanes 0..53)
        if (lane < 54) {
            const int cl  = lane >> 1;
            const int sub = lane & 1;
            const int cx = hcx + (cl % 3) - 1;
            const int cy = hcy + ((cl / 3) % 3) - 1;
            const int cz = hcz + (cl / 9) - 1;
            if (cx >= 0 && cx < GRIDC && cy >= 0 && cy < GRIDC &&
                cz >= 0 && cz < GRIDC) {
                const int cell = cbase + (cz * GRIDC + cy) * GRIDC + cx;
                const int n = min(cnt[(size_t)cell * CS], CAP);
                const float4* bp = buckets + (size_t)cell * CAP;
                for (int k = sub; k < n; k += 2) {   // independent 16B loads
                    const float4 p = bp[k];
                    const float dx = p.x - hx, dy = p.y - hy, dz = p.z - hz;
                    best = fminf(best, fmaf(dx, dx, fmaf(dy, dy, dz * dz)));
                }
            }
        }

        // overflow list (normally empty), lane-strided
        const int on = *ocnt;
        for (int k = lane; k < on; k += 64) {
            const float4 p = ovf[k];
            if (__float_as_int(p.w) == b) {
                const float dx = p.x - hx, dy = p.y - hy, dz = p.z - hz;
                best = fminf(best, fmaf(dx, dx, fmaf(dy, dy, dz * dz)));
            }
        }

#pragma unroll
        for (int d = 1; d < 64; d <<= 1) best = fminf(best, __shfl_xor(best, d));

        // rare path: expanding shells, lane-strided over shell cells
        for (int r = 2; r < GRIDC; ++r) {
            const float bnd = (float)(r - 1) * CELL;
            if (best <= bnd * bnd) break;
            const int side = 2 * r + 1;
            const int ncells = side * side * side;
            for (int ci = lane; ci < ncells; ci += 64) {
                const int dx = ci % side - r;
                const int dy = (ci / side) % side - r;
                const int dz = ci / (side * side) - r;
                if (max(max(abs(dx), abs(dy)), abs(dz)) != r) continue; // shell only
                const int cx = hcx + dx, cy = hcy + dy, cz = hcz + dz;
                if (cx < 0 || cx >= GRIDC || cy < 0 || cy >= GRIDC ||
                    cz < 0 || cz >= GRIDC) continue;
                const int cell = cbase + (cz * GRIDC + cy) * GRIDC + cx;
                const int n = min(cnt[(size_t)cell * CS], CAP);
                const float4* bp = buckets + (size_t)cell * CAP;
                for (int k = 0; k < n; ++k) {
                    const float4 p = bp[k];
                    const float ddx = p.x - hx, ddy = p.y - hy, ddz = p.z - hz;
                    best = fminf(best, fmaf(ddx, ddx, fmaf(ddy, ddy, ddz * ddz)));
                }
            }
#pragma unroll
            for (int d = 1; d < 64; d <<= 1) best = fminf(best, __shfl_xor(best, d));
        }
    }

    // ---- fused finalize: per-block stat reduction ----
    __shared__ double ssd[4], ssp[4], ssa[4];
    __shared__ int scp[4], sca[4];
    if (lane == 0) {
        double sd = 0.0, sp = 0.0, sa = 0.0;
        int cp = 0, ca = 0;
        if (valid) {
            const float d = sqrtf(fmaxf(best, 0.f));
            sd = (double)d;
            if (d < COLL) { const float t = COLL - d; sp = (double)(t * t); cp = 1; }
            const int n = i % NH;
            const bool isc = (n == 745) | (n == 317) | (n == 444) | (n == 556) |
                             (n == 673) | (n == 95)  | (n == 182) | (n == 234) |
                             (n == 279) | (n == 320);
            if (isc & (d > COLL) & (d < CONT)) { sa = (double)(d * d); ca = 1; }
        }
        ssd[wave] = sd; ssp[wave] = sp; ssa[wave] = sa;
        scp[wave] = cp; sca[wave] = ca;
    }
    __syncthreads();
    if (tid == 0) {
        const double sd = ssd[0] + ssd[1] + ssd[2] + ssd[3];
        const double sp = ssp[0] + ssp[1] + ssp[2] + ssp[3];
        const double sa = ssa[0] + ssa[1] + ssa[2] + ssa[3];
        const int cp = scp[0] + scp[1] + scp[2] + scp[3];
        const int ca = sca[0] + sca[1] + sca[2] + sca[3];
        const int sh = (int)(blockIdx.x & (NSH - 1));
        atomicAdd(&shd[sh * 3 + 0], sd);
        atomicAdd(&shd[sh * 3 + 1], sp);
        atomicAdd(&shd[sh * 3 + 2], sa);
        atomicAdd(&shi[sh * 2 + 0], cp);
        atomicAdd(&shi[sh * 2 + 1], ca);
        __threadfence();
        const int t = atomicAdd(ticket, 1);
        if (t == (int)gridDim.x - 1) {
            __threadfence();
            double fsd = 0.0, fsp = 0.0, fsa = 0.0;
            int fcp = 0, fca = 0;
            for (int s = 0; s < NSH; ++s) {
                fsd += __hip_atomic_load(&shd[s * 3 + 0], __ATOMIC_RELAXED, __HIP_MEMORY_SCOPE_AGENT);
                fsp += __hip_atomic_load(&shd[s * 3 + 1], __ATOMIC_RELAXED, __HIP_MEMORY_SCOPE_AGENT);
                fsa += __hip_atomic_load(&shd[s * 3 + 2], __ATOMIC_RELAXED, __HIP_MEMORY_SCOPE_AGENT);
                fcp += __hip_atomic_load(&shi[s * 2 + 0], __ATOMIC_RELAXED, __HIP_MEMORY_SCOPE_AGENT);
                fca += __hip_atomic_load(&shi[s * 2 + 1], __ATOMIC_RELAXED, __HIP_MEMORY_SCOPE_AGENT);
            }
            const double pen_loss = fcp > 0 ? fsp / (double)fcp : 0.0;
            const double att_loss = fca > 0 ? fsa / (double)fca : 0.0;
            out[0] = (float)(100.0 * pen_loss + 10.0 * att_loss);
            out[1] = (float)pen_loss;
            out[2] = (float)att_loss;
            out[3] = (float)(fsd / (double)nq);
            out[4] = (float)fca;
            out[5] = (float)fcp;
        }
    }
}

// ---------------------------------------------------------------------------
// Fallback brute-force (R10 kernel) if ws is too small for the grid. Writes
// uint bit-pattern mins of d2 — identical representation to plain float d2.
// ---------------------------------------------------------------------------
typedef float v2f __attribute__((ext_vector_type(2)));
constexpr int FT = 16, FG = 4, FBLK = 256, FCHUNK = 2560;
constexpr int FNBX = (NH + FG * FT - 1) / (FG * FT);
constexpr int FLPP = FCHUNK / FBLK, FPP = FLPP / 2;

__global__ __launch_bounds__(FBLK, 2) void nn_brute_kernel(
    const float* __restrict__ hand, const float* __restrict__ obj,
    unsigned int* __restrict__ minb, int V)
{
    __shared__ float s_red[4][16 * 65];
    const int bx = blockIdx.x, c = blockIdx.y, b = blockIdx.z;
    const int tid = threadIdx.x, wave = tid >> 6, lane = tid & 63;
    const int r = lane & 15, seg = lane >> 4;
    const float* ob = obj + (size_t)b * V * 3;
    const int base = c * FCHUNK + tid;
    v2f ox2[FPP], oy2[FPP], oz2[FPP], oq2[FPP];
#pragma unroll
    for (int p = 0; p < FPP; ++p) {
        const int ja = min(base + (2 * p + 0) * FBLK, V - 1);
        const int jb = min(base + (2 * p + 1) * FBLK, V - 1);
        const float xa = ob[3 * ja], ya = ob[3 * ja + 1], za = ob[3 * ja + 2];
        const float xb = ob[3 * jb], yb = ob[3 * jb + 1], zb = ob[3 * jb + 2];
        ox2[p] = (v2f){-2.f * xa, -2.f * xb};
        oy2[p] = (v2f){-2.f * ya, -2.f * yb};
        oz2[p] = (v2f){-2.f * za, -2.f * zb};
        oq2[p] = (v2f){fmaf(xa, xa, fmaf(ya, ya, za * za)),
                       fmaf(xb, xb, fmaf(yb, yb, zb * zb))};
    }
    const float* hb = hand + (size_t)b * NH * 3;
    float* sw = &s_red[wave][0];
#pragma unroll 1
    for (int g = 0; g < FG; ++g) {
        float hx[FT], hy[FT], hz[FT], m[FT];
#pragma unroll
        for (int t = 0; t < FT; ++t) {
            const int h = min((bx * FG + g) * FT + t, NH - 1);
            hx[t] = hb[3 * h]; hy[t] = hb[3 * h + 1]; hz[t] = hb[3 * h + 2];
            m[t] = 3.4e38f;
        }
#pragma unroll
        for (int p = 0; p < FPP; ++p) {
#pragma unroll
            for (int t = 0; t < FT; ++t) {
                v2f a = __builtin_elementwise_fma(ox2[p], (v2f){hx[t], hx[t]}, oq2[p]);
                a = __builtin_elementwise_fma(oy2[p], (v2f){hy[t], hy[t]}, a);
                a = __builtin_elementwise_fma(oz2[p], (v2f){hz[t], hz[t]}, a);
                m[t] = fminf(fminf(a.x, a.y), m[t]);
            }
        }
#pragma unroll
        for (int t = 0; t < FT; ++t) {
            const float hq = fmaf(hx[t], hx[t], fmaf(hy[t], hy[t], hz[t] * hz[t]));
            sw[t * 65 + lane] = m[t] + hq;
        }
        __builtin_amdgcn_wave_barrier();
        float v = 3.4e38f;
        const int rb = r * 65 + seg * 16;
#pragma unroll
        for (int j = 0; j < 16; ++j) v = fminf(v, sw[rb + j]);
        __builtin_amdgcn_wave_barrier();
        v = fminf(v, __shfl_xor(v, 16));
        v = fminf(v, __shfl_xor(v, 32));
        if (seg == 0) {
            const int hidx = (bx * FG + g) * FT + r;
            if (hidx < NH) {
                const unsigned bits = __float_as_uint(fmaxf(v, 0.f));
                unsigned int* p = &minb[b * NH + hidx];
                if (bits < *((volatile unsigned int*)p)) atomicMin(p, bits);
            }
        }
    }
}

// ---------------------------------------------------------------------------
// Final reduction for the FALLBACK path only (dist buffer holds d2 floats)
// ---------------------------------------------------------------------------
__global__ __launch_bounds__(256) void finalize_kernel(
    const float* __restrict__ dist, float* __restrict__ out, int B)
{
    constexpr float COLL = 0.005f;
    constexpr float CONT = 0.01f;
    const int total = B * NH;
    const int tid = threadIdx.x;

    double sum_d = 0.0, pen_sum = 0.0, att_sum = 0.0;
    int pen_cnt = 0, att_cnt = 0;
    for (int i = tid; i < total; i += 256) {
        const float d = sqrtf(fmaxf(dist[i], 0.f));
        sum_d += (double)d;
        if (d < COLL) { const float t = COLL - d; pen_sum += (double)(t * t); pen_cnt++; }
        const int n = i % NH;
        const bool isc = (n == 745) | (n == 317) | (n == 444) | (n == 556) |
                         (n == 673) | (n == 95)  | (n == 182) | (n == 234) |
                         (n == 279) | (n == 320);
        if (isc & (d > COLL) & (d < CONT)) { att_sum += (double)(d * d); att_cnt++; }
    }

    __shared__ double sd[256], sp[256], sa[256];
    __shared__ int    cp[256], ca[256];
    sd[tid] = sum_d; sp[tid] = pen_sum; sa[tid] = att_sum;
    cp[tid] = pen_cnt; ca[tid] = att_cnt;
    __syncthreads();
    for (int off = 128; off > 0; off >>= 1) {
        if (tid < off) {
            sd[tid] += sd[tid + off]; sp[tid] += sp[tid + off];
            sa[tid] += sa[tid + off];
            cp[tid] += cp[tid + off]; ca[tid] += ca[tid + off];
        }
        __syncthreads();
    }
    if (tid == 0) {
        const double pen_loss = cp[0] > 0 ? sp[0] / (double)cp[0] : 0.0;
        const double att_loss = ca[0] > 0 ? sa[0] / (double)ca[0] : 0.0;
        out[0] = (float)(100.0 * pen_loss + 10.0 * att_loss);
        out[1] = (float)pen_loss;
        out[2] = (float)att_loss;
        out[3] = (float)(sd[0] / (double)total);
        out[4] = (float)ca[0];
        out[5] = (float)cp[0];
    }
}

extern "C" void kernel_launch(void* const* d_in, const int* in_sizes, int n_in,
                              void* d_out, int out_size, void* d_ws, size_t ws_size,
                              hipStream_t stream) {
    const float* hand = (const float*)d_in[0];  // [B, 778, 3] fp32
    const float* obj  = (const float*)d_in[1];  // [B, V, 3]   fp32
    // d_in[2]/d_in[3] (faces): unused by the loss

    const int B = in_sizes[0] / (NH * 3);
    const int V = in_sizes[1] / (B * 3);
    const int total = B * V;
    const int nq = B * NH;

    // workspace layout
    char* base = (char*)d_ws;
    size_t off = 65536;                         // [0,64K): fallback minb/dist region
    int*    ticket = (int*)(base + off);                           // 1 int
    int*    ocnt   = (int*)(base + off + 4);                       // 1 int
    double* shd    = (double*)(base + off + 64);                   // [NSH][3] f64
    int*    shi    = (int*)(base + off + 64 + NSH * 3 * 8);        // [NSH][2] int
    int*    cnt    = (int*)(base + off + 4096);                    // [B*NCELL*CS]
    const size_t cnt_bytes = (size_t)B * NCELL * CS * sizeof(int);
    const size_t boff = (off + 4096 + cnt_bytes + 255) & ~(size_t)255;
    float4* buckets = (float4*)(base + boff);                      // [B*NCELL*CAP]
    const size_t bkt_bytes = (size_t)B * NCELL * CAP * sizeof(float4);
    float4* ovf = (float4*)(base + boff + bkt_bytes);              // [B*V] worst case
    const size_t need = boff + bkt_bytes + (size_t)total * sizeof(float4);

    if (ws_size >= need) {
        // zero ticket + ocnt + shards + cell counts in ONE small fill (~2.1 MB)
        hipMemsetAsync(base + off, 0, 4096 + cnt_bytes, stream);
        bin_kernel<<<(total + 255) / 256, 256, 0, stream>>>(
            obj, cnt, ocnt, buckets, ovf, total, V);
        const int qblocks = (nq * 64 + 255) / 256;   // one wave per query, 4/block
        query_fused_kernel<<<qblocks, 256, 0, stream>>>(
            hand, cnt, buckets, ovf, ocnt, shd, shi, ticket, (float*)d_out, nq, B);
    } else {
        // brute-force fallback (uint bit-pattern mins == float d2)
        hipMemsetAsync(d_ws, 0x7F, (size_t)nq * sizeof(unsigned int), stream);
        dim3 grid(FNBX, (V + FCHUNK - 1) / FCHUNK, B);
        nn_brute_kernel<<<grid, FBLK, 0, stream>>>(hand, obj,
                                                   (unsigned int*)d_ws, V);
        finalize_kernel<<<1, 256, 0, stream>>>((const float*)d_ws, (float*)d_out, B);
    }
}

// Round 2
// 95.558 us; speedup vs baseline: 1.3610x; 1.3610x over previous
//
#include <hip/hip_runtime.h>
#include <math.h>

// Problem constants
constexpr int NH    = 778;           // hand verts per batch
constexpr int GRIDC = 16;            // cells per axis (0.1 m cube -> 6.25 mm cells)
constexpr int NCELL = GRIDC * GRIDC * GRIDC;   // 4096
constexpr int CAP   = 40;            // bucket cap (Poisson mean ~9.8; P(>40)~1e-14)
constexpr float CELL     = 0.1f / GRIDC;       // 0.00625
constexpr float INV_CELL = GRIDC / 0.1f;       // 160
constexpr int NXCD = 8;              // MI355X XCD count (bid%8 ~ XCD heuristic)

// R13: reverted R12's CS=16 + ticket fusion (regression 100->130us: 1556
// same-address ticket atomics serialized ~35us tail; CS=16 spread query cnt
// reads over 27 lines). Back to R11 structure + ONE change: XCD-affinity
// work remap so batch b is written (bin) and read (query) by XCD b only.

__device__ __forceinline__ int clampc(int v) {
    return min(GRIDC - 1, max(0, v));
}

// ---------------------------------------------------------------------------
// K1: bin obj points into per-(batch,cell) buckets. Overflow (idx >= CAP)
// goes to a global list tagged with batch (capacity = ALL points -> always
// exact for any distribution). Insertion order is atomic-nondeterministic;
// min over the union is order-independent.
// R13: work remap (bid%8 -> XCD chunk) gives each XCD one batch: bucket
// lines receive all ~4 writes from ONE XCD's L2 instead of ping-ponging.
// ---------------------------------------------------------------------------
__global__ __launch_bounds__(256) void bin_kernel(
    const float* __restrict__ obj,   // [B, V, 3] flat
    int* __restrict__ cnt,           // [B*NCELL]
    int* __restrict__ ocnt,          // overflow counter
    float4* __restrict__ buckets,    // [B*NCELL*CAP]
    float4* __restrict__ ovf,        // [B*V] worst case
    int B, int V, int bpb)           // bpb = blocks per batch
{
    // bijective remap (gridDim.x % 8 == 0, launcher-enforced):
    // consecutive w on the SAME XCD; w/bpb = batch (B==8 -> batch==XCD).
    const int w = (blockIdx.x % NXCD) * (gridDim.x / NXCD) + blockIdx.x / NXCD;
    const int b = w / bpb;
    const int p = (w % bpb) * 256 + threadIdx.x;
    if (b >= B || p >= V) return;
    const int i = b * V + p;

    const float x = obj[3 * i + 0];
    const float y = obj[3 * i + 1];
    const float z = obj[3 * i + 2];
    const int cx = clampc((int)(x * INV_CELL));
    const int cy = clampc((int)(y * INV_CELL));
    const int cz = clampc((int)(z * INV_CELL));
    const int cell = b * NCELL + (cz * GRIDC + cy) * GRIDC + cx;
    const int idx = atomicAdd(&cnt[cell], 1);
    if (idx < CAP) {
        buckets[(size_t)cell * CAP + idx] = make_float4(x, y, z, 0.f);
    } else {
        const int oi = atomicAdd(ocnt, 1);   // oi < total always
        ovf[oi] = make_float4(x, y, z, __int_as_float(b));
    }
}

// ---------------------------------------------------------------------------
// K2: exact grid NN query — ONE WAVE PER QUERY. R13: same XCD-affinity remap
// as bin, so batch b's buckets (2.6MB) + cnt (16KB) live in XCD b's 4MB L2.
// Exactness: h lies inside its own cell, so after completing cube radius r-1
// every unscanned point is >= (r-1)*CELL away; stop iff best <= ((r-1)*CELL)^2.
// Radius-1 cube suffices for ~all queries (E[NN] ~1.6mm << 6.25mm cell).
// ---------------------------------------------------------------------------
__global__ __launch_bounds__(256) void query_kernel(
    const float* __restrict__ hand,    // [B, NH, 3] flat
    const int* __restrict__ cnt,       // [B*NCELL]
    const float4* __restrict__ buckets,// [B*NCELL*CAP]
    const float4* __restrict__ ovf,
    const int* __restrict__ ocnt,
    float* __restrict__ dist,          // [B*NH] min d2
    int B, int bpq)                    // bpq = blocks per batch (4 queries/block)
{
    const int tid  = threadIdx.x;
    const int wave = tid >> 6;
    const int lane = tid & 63;
    const int w = (blockIdx.x % NXCD) * (gridDim.x / NXCD) + blockIdx.x / NXCD;
    const int b  = w / bpq;
    const int ql = (w % bpq) * 4 + wave;    // local query id in batch
    if (b >= B || ql >= NH) return;
    const int i = b * NH + ql;

    const float hx = hand[3 * i + 0];
    const float hy = hand[3 * i + 1];
    const float hz = hand[3 * i + 2];
    const int hcx = clampc((int)(hx * INV_CELL));
    const int hcy = clampc((int)(hy * INV_CELL));
    const int hcz = clampc((int)(hz * INV_CELL));
    const int cbase = b * NCELL;

    float best = 3.4e38f;

    // phase 1: radius-1 cube (27 cells), 2 lanes per cell (lanes 0..53)
    if (lane < 54) {
        const int cl  = lane >> 1;
        const int sub = lane & 1;
        const int cx = hcx + (cl % 3) - 1;
        const int cy = hcy + ((cl / 3) % 3) - 1;
        const int cz = hcz + (cl / 9) - 1;
        if (cx >= 0 && cx < GRIDC && cy >= 0 && cy < GRIDC &&
            cz >= 0 && cz < GRIDC) {
            const int cell = cbase + (cz * GRIDC + cy) * GRIDC + cx;
            const int n = min(cnt[cell], CAP);
            const float4* bp = buckets + (size_t)cell * CAP;
            for (int k = sub; k < n; k += 2) {   // independent 16B loads
                const float4 p = bp[k];
                const float dx = p.x - hx, dy = p.y - hy, dz = p.z - hz;
                best = fminf(best, fmaf(dx, dx, fmaf(dy, dy, dz * dz)));
            }
        }
    }

    // overflow list (normally empty), lane-strided
    const int on = *ocnt;
    for (int k = lane; k < on; k += 64) {
        const float4 p = ovf[k];
        if (__float_as_int(p.w) == b) {
            const float dx = p.x - hx, dy = p.y - hy, dz = p.z - hz;
            best = fminf(best, fmaf(dx, dx, fmaf(dy, dy, dz * dz)));
        }
    }

#pragma unroll
    for (int d = 1; d < 64; d <<= 1) best = fminf(best, __shfl_xor(best, d));

    // rare path: expanding shells, lane-strided over shell cells
    for (int r = 2; r < GRIDC; ++r) {
        const float bnd = (float)(r - 1) * CELL;
        if (best <= bnd * bnd) break;
        const int side = 2 * r + 1;
        const int ncells = side * side * side;
        for (int ci = lane; ci < ncells; ci += 64) {
            const int dx = ci % side - r;
            const int dy = (ci / side) % side - r;
            const int dz = ci / (side * side) - r;
            if (max(max(abs(dx), abs(dy)), abs(dz)) != r) continue; // shell only
            const int cx = hcx + dx, cy = hcy + dy, cz = hcz + dz;
            if (cx < 0 || cx >= GRIDC || cy < 0 || cy >= GRIDC ||
                cz < 0 || cz >= GRIDC) continue;
            const int cell = cbase + (cz * GRIDC + cy) * GRIDC + cx;
            const int n = min(cnt[cell], CAP);
            const float4* bp = buckets + (size_t)cell * CAP;
            for (int k = 0; k < n; ++k) {
                const float4 p = bp[k];
                const float ddx = p.x - hx, ddy = p.y - hy, ddz = p.z - hz;
                best = fminf(best, fmaf(ddx, ddx, fmaf(ddy, ddy, ddz * ddz)));
            }
        }
#pragma unroll
        for (int d = 1; d < 64; d <<= 1) best = fminf(best, __shfl_xor(best, d));
    }

    if (lane == 0) dist[i] = best;
}

// ---------------------------------------------------------------------------
// Fallback brute-force (R10 kernel) if ws is too small for the grid. Writes
// uint bit-pattern mins of d2 — identical representation to plain float d2.
// ---------------------------------------------------------------------------
typedef float v2f __attribute__((ext_vector_type(2)));
constexpr int FT = 16, FG = 4, FBLK = 256, FCHUNK = 2560;
constexpr int FNBX = (NH + FG * FT - 1) / (FG * FT);
constexpr int FLPP = FCHUNK / FBLK, FPP = FLPP / 2;

__global__ __launch_bounds__(FBLK, 2) void nn_brute_kernel(
    const float* __restrict__ hand, const float* __restrict__ obj,
    unsigned int* __restrict__ minb, int V)
{
    __shared__ float s_red[4][16 * 65];
    const int bx = blockIdx.x, c = blockIdx.y, b = blockIdx.z;
    const int tid = threadIdx.x, wave = tid >> 6, lane = tid & 63;
    const int r = lane & 15, seg = lane >> 4;
    const float* ob = obj + (size_t)b * V * 3;
    const int base = c * FCHUNK + tid;
    v2f ox2[FPP], oy2[FPP], oz2[FPP], oq2[FPP];
#pragma unroll
    for (int p = 0; p < FPP; ++p) {
        const int ja = min(base + (2 * p + 0) * FBLK, V - 1);
        const int jb = min(base + (2 * p + 1) * FBLK, V - 1);
        const float xa = ob[3 * ja], ya = ob[3 * ja + 1], za = ob[3 * ja + 2];
        const float xb = ob[3 * jb], yb = ob[3 * jb + 1], zb = ob[3 * jb + 2];
        ox2[p] = (v2f){-2.f * xa, -2.f * xb};
        oy2[p] = (v2f){-2.f * ya, -2.f * yb};
        oz2[p] = (v2f){-2.f * za, -2.f * zb};
        oq2[p] = (v2f){fmaf(xa, xa, fmaf(ya, ya, za * za)),
                       fmaf(xb, xb, fmaf(yb, yb, zb * zb))};
    }
    const float* hb = hand + (size_t)b * NH * 3;
    float* sw = &s_red[wave][0];
#pragma unroll 1
    for (int g = 0; g < FG; ++g) {
        float hx[FT], hy[FT], hz[FT], m[FT];
#pragma unroll
        for (int t = 0; t < FT; ++t) {
            const int h = min((bx * FG + g) * FT + t, NH - 1);
            hx[t] = hb[3 * h]; hy[t] = hb[3 * h + 1]; hz[t] = hb[3 * h + 2];
            m[t] = 3.4e38f;
        }
#pragma unroll
        for (int p = 0; p < FPP; ++p) {
#pragma unroll
            for (int t = 0; t < FT; ++t) {
                v2f a = __builtin_elementwise_fma(ox2[p], (v2f){hx[t], hx[t]}, oq2[p]);
                a = __builtin_elementwise_fma(oy2[p], (v2f){hy[t], hy[t]}, a);
                a = __builtin_elementwise_fma(oz2[p], (v2f){hz[t], hz[t]}, a);
                m[t] = fminf(fminf(a.x, a.y), m[t]);
            }
        }
#pragma unroll
        for (int t = 0; t < FT; ++t) {
            const float hq = fmaf(hx[t], hx[t], fmaf(hy[t], hy[t], hz[t] * hz[t]));
            sw[t * 65 + lane] = m[t] + hq;
        }
        __builtin_amdgcn_wave_barrier();
        float v = 3.4e38f;
        const int rb = r * 65 + seg * 16;
#pragma unroll
        for (int j = 0; j < 16; ++j) v = fminf(v, sw[rb + j]);
        __builtin_amdgcn_wave_barrier();
        v = fminf(v, __shfl_xor(v, 16));
        v = fminf(v, __shfl_xor(v, 32));
        if (seg == 0) {
            const int hidx = (bx * FG + g) * FT + r;
            if (hidx < NH) {
                const unsigned bits = __float_as_uint(fmaxf(v, 0.f));
                unsigned int* p = &minb[b * NH + hidx];
                if (bits < *((volatile unsigned int*)p)) atomicMin(p, bits);
            }
        }
    }
}

// ---------------------------------------------------------------------------
// Final reduction -> 6 scalar outputs (dist buffer holds d2 as plain floats)
// ---------------------------------------------------------------------------
__global__ __launch_bounds__(256) void finalize_kernel(
    const float* __restrict__ dist, float* __restrict__ out, int B)
{
    constexpr float COLL = 0.005f;
    constexpr float CONT = 0.01f;
    const int total = B * NH;
    const int tid = threadIdx.x;

    double sum_d = 0.0, pen_sum = 0.0, att_sum = 0.0;
    int pen_cnt = 0, att_cnt = 0;
    for (int i = tid; i < total; i += 256) {
        const float d = sqrtf(fmaxf(dist[i], 0.f));
        sum_d += (double)d;
        if (d < COLL) { const float t = COLL - d; pen_sum += (double)(t * t); pen_cnt++; }
        const int n = i % NH;
        const bool isc = (n == 745) | (n == 317) | (n == 444) | (n == 556) |
                         (n == 673) | (n == 95)  | (n == 182) | (n == 234) |
                         (n == 279) | (n == 320);
        if (isc & (d > COLL) & (d < CONT)) { att_sum += (double)(d * d); att_cnt++; }
    }

    __shared__ double sd[256], sp[256], sa[256];
    __shared__ int    cp[256], ca[256];
    sd[tid] = sum_d; sp[tid] = pen_sum; sa[tid] = att_sum;
    cp[tid] = pen_cnt; ca[tid] = att_cnt;
    __syncthreads();
    for (int off = 128; off > 0; off >>= 1) {
        if (tid < off) {
            sd[tid] += sd[tid + off]; sp[tid] += sp[tid + off];
            sa[tid] += sa[tid + off];
            cp[tid] += cp[tid + off]; ca[tid] += ca[tid + off];
        }
        __syncthreads();
    }
    if (tid == 0) {
        const double pen_loss = cp[0] > 0 ? sp[0] / (double)cp[0] : 0.0;
        const double att_loss = ca[0] > 0 ? sa[0] / (double)ca[0] : 0.0;
        out[0] = (float)(100.0 * pen_loss + 10.0 * att_loss);
        out[1] = (float)pen_loss;
        out[2] = (float)att_loss;
        out[3] = (float)(sd[0] / (double)total);
        out[4] = (float)ca[0];
        out[5] = (float)cp[0];
    }
}

extern "C" void kernel_launch(void* const* d_in, const int* in_sizes, int n_in,
                              void* d_out, int out_size, void* d_ws, size_t ws_size,
                              hipStream_t stream) {
    const float* hand = (const float*)d_in[0];  // [B, 778, 3] fp32
    const float* obj  = (const float*)d_in[1];  // [B, V, 3]   fp32
    // d_in[2]/d_in[3] (faces): unused by the loss

    const int B = in_sizes[0] / (NH * 3);
    const int V = in_sizes[1] / (B * 3);
    const int total = B * V;

    // workspace layout (R11/R0 layout, CS=1)
    float* dist = (float*)d_ws;                                   // [B*NH]
    char* base = (char*)d_ws;
    size_t off = 65536;
    int* cnt = (int*)(base + off);                                // [B*NCELL]
    const size_t cnt_bytes = (size_t)B * NCELL * sizeof(int);
    int* ocnt = (int*)(base + off + cnt_bytes);                   // 1 int
    size_t boff = (off + cnt_bytes + 256) & ~(size_t)255;
    float4* buckets = (float4*)(base + boff);                     // [B*NCELL*CAP]
    const size_t bkt_bytes = (size_t)B * NCELL * CAP * sizeof(float4);
    float4* ovf = (float4*)(base + boff + bkt_bytes);             // [B*V] worst case
    const size_t need = boff + bkt_bytes + (size_t)total * sizeof(float4);

    if (ws_size >= need) {
        // zero cell counts + overflow counter (one small fill)
        hipMemsetAsync(cnt, 0, cnt_bytes + 64, stream);

        // bin with XCD-affinity remap: grid padded to %8, bpb blocks/batch
        const int bpb = (V + 255) / 256;
        int gbin = B * bpb; gbin = (gbin + NXCD - 1) & ~(NXCD - 1);
        bin_kernel<<<gbin, 256, 0, stream>>>(obj, cnt, ocnt, buckets, ovf,
                                             B, V, bpb);

        // query with the SAME batch->XCD mapping (4 waves/block, 1 wave/query)
        const int bpq = (NH + 3) / 4;   // 195
        int gq = B * bpq; gq = (gq + NXCD - 1) & ~(NXCD - 1);
        query_kernel<<<gq, 256, 0, stream>>>(hand, cnt, buckets, ovf, ocnt,
                                             dist, B, bpq);
    } else {
        // brute-force fallback (uint bit-pattern mins == float d2)
        hipMemsetAsync(d_ws, 0x7F, (size_t)B * NH * sizeof(unsigned int), stream);
        dim3 grid(FNBX, (V + FCHUNK - 1) / FCHUNK, B);
        nn_brute_kernel<<<grid, FBLK, 0, stream>>>(hand, obj,
                                                   (unsigned int*)d_ws, V);
    }
    finalize_kernel<<<1, 256, 0, stream>>>(dist, (float*)d_out, B);
}

// Round 3
// 88.426 us; speedup vs baseline: 1.4707x; 1.0806x over previous
//
#include <hip/hip_runtime.h>
#include <math.h>

// Problem constants
constexpr int NH    = 778;           // hand verts per batch
constexpr int GRIDC = 16;            // cells per axis (0.1 m cube -> 6.25 mm cells)
constexpr int NCELL = GRIDC * GRIDC * GRIDC;   // 4096
constexpr int CAP   = 40;            // bucket cap (Poisson mean ~9.8; P(>40)~1e-14)
                                     // NOTE: CAP reduction is useless — only the first
                                     // ~2.5 lines/cell are ever touched, RFO is the same.
constexpr float CELL     = 0.1f / GRIDC;       // 0.00625
constexpr float INV_CELL = GRIDC / 0.1f;       // 160
constexpr int NXCD = 8;              // MI355X XCD count (bid%8 ~ XCD heuristic)
constexpr int NSH  = 64;             // stat shards, one 64B line each

// R14: (a) bin 4 pts/thread via aligned float4 loads — bin was issue/dep-chain
// bound (atomicAdd-return -> dependent store), not BW-bound; (b) query blocks
// accumulate stats into 64 line-padded shards with RELAXED atomics (no fence,
// no ticket — R12's 40us tail was the ticket+threadfence, not stat fusion),
// then a 1-wave finalize_tiny replaces the 25-round single-block finalize.

struct alignas(64) Shard {
    double sd, sp, sa;   // sum_d, pen_sum, att_sum
    int cp, ca;          // pen_cnt, att_cnt
    int pad[3];
};

__device__ __forceinline__ int clampc(int v) {
    return min(GRIDC - 1, max(0, v));
}

// ---------------------------------------------------------------------------
// K1: bin obj points into per-(batch,cell) buckets. 4 points per thread.
// Overflow (idx >= CAP) goes to a global list tagged with batch (capacity =
// ALL points -> always exact). XCD-affinity remap: batch b on XCD b (B==8).
// ---------------------------------------------------------------------------
__global__ __launch_bounds__(256) void bin_kernel(
    const float* __restrict__ obj,   // [B, V, 3] flat
    int* __restrict__ cnt,           // [B*NCELL]
    int* __restrict__ ocnt,          // overflow counter
    float4* __restrict__ buckets,    // [B*NCELL*CAP]
    float4* __restrict__ ovf,        // [B*V] worst case
    int B, int V, int bpb)           // bpb = blocks per batch (1024 pts/block)
{
    const int w = (blockIdx.x % NXCD) * (gridDim.x / NXCD) + blockIdx.x / NXCD;
    const int b = w / bpb;
    if (b >= B) return;
    const int p0 = ((w % bpb) * 256 + (int)threadIdx.x) * 4;
    if (p0 >= V) return;

    float px[4], py[4], pz[4];
    int np;
    const size_t fbase = ((size_t)b * V + p0) * 3;
    if (p0 + 4 <= V && (fbase & 3) == 0) {
        // 3x float4 = 12 floats = 4 points, 16B-aligned (p0%4==0, V*3%4==0 here)
        const float4* src = (const float4*)(obj + fbase);
        const float4 A = src[0], Bv = src[1], C = src[2];
        px[0]=A.x;  py[0]=A.y;  pz[0]=A.z;
        px[1]=A.w;  py[1]=Bv.x; pz[1]=Bv.y;
        px[2]=Bv.z; py[2]=Bv.w; pz[2]=C.x;
        px[3]=C.y;  py[3]=C.z;  pz[3]=C.w;
        np = 4;
    } else {
        np = min(4, V - p0);
        for (int q = 0; q < np; ++q) {
            px[q] = obj[fbase + 3 * q + 0];
            py[q] = obj[fbase + 3 * q + 1];
            pz[q] = obj[fbase + 3 * q + 2];
        }
    }

    const int cb = b * NCELL;
#pragma unroll
    for (int q = 0; q < 4; ++q) {
        if (q >= np) break;
        const int cx = clampc((int)(px[q] * INV_CELL));
        const int cy = clampc((int)(py[q] * INV_CELL));
        const int cz = clampc((int)(pz[q] * INV_CELL));
        const int cell = cb + (cz * GRIDC + cy) * GRIDC + cx;
        const int idx = atomicAdd(&cnt[cell], 1);
        if (idx < CAP) {
            buckets[(size_t)cell * CAP + idx] = make_float4(px[q], py[q], pz[q], 0.f);
        } else {
            const int oi = atomicAdd(ocnt, 1);   // oi < total always
            ovf[oi] = make_float4(px[q], py[q], pz[q], __int_as_float(b));
        }
    }
}

// ---------------------------------------------------------------------------
// K2: exact grid NN query — ONE WAVE PER QUERY — with fused stat accumulation
// into padded shards (relaxed atomics, no fence: kernel-boundary visibility).
// Exactness: h lies inside its own cell, so after completing cube radius r-1
// every unscanned point is >= (r-1)*CELL away; stop iff best <= ((r-1)*CELL)^2.
// ---------------------------------------------------------------------------
__global__ __launch_bounds__(256) void query_kernel(
    const float* __restrict__ hand,    // [B, NH, 3] flat
    const int* __restrict__ cnt,       // [B*NCELL]
    const float4* __restrict__ buckets,// [B*NCELL*CAP]
    const float4* __restrict__ ovf,
    const int* __restrict__ ocnt,
    Shard* __restrict__ shards,        // [NSH]
    int B, int bpq)                    // bpq = blocks per batch (4 queries/block)
{
    constexpr float COLL = 0.005f;
    constexpr float CONT = 0.01f;
    const int tid  = threadIdx.x;
    const int wave = tid >> 6;
    const int lane = tid & 63;
    const int w  = (blockIdx.x % NXCD) * (gridDim.x / NXCD) + blockIdx.x / NXCD;
    const int b  = w / bpq;
    const int ql = (w % bpq) * 4 + wave;    // local query id in batch
    const bool valid = (b < B) && (ql < NH);

    float best = 3.4e38f;

    if (valid) {
        const int i = b * NH + ql;
        const float hx = hand[3 * i + 0];
        const float hy = hand[3 * i + 1];
        const float hz = hand[3 * i + 2];
        const int hcx = clampc((int)(hx * INV_CELL));
        const int hcy = clampc((int)(hy * INV_CELL));
        const int hcz = clampc((int)(hz * INV_CELL));
        const int cbase = b * NCELL;

        // phase 1: radius-1 cube (27 cells), 2 lanes per cell (lanes 0..53)
        if (lane < 54) {
            const int cl  = lane >> 1;
            const int sub = lane & 1;
            const int cx = hcx + (cl % 3) - 1;
            const int cy = hcy + ((cl / 3) % 3) - 1;
            const int cz = hcz + (cl / 9) - 1;
            if (cx >= 0 && cx < GRIDC && cy >= 0 && cy < GRIDC &&
                cz >= 0 && cz < GRIDC) {
                const int cell = cbase + (cz * GRIDC + cy) * GRIDC + cx;
                const int n = min(cnt[cell], CAP);
                const float4* bp = buckets + (size_t)cell * CAP;
                for (int k = sub; k < n; k += 2) {   // independent 16B loads
                    const float4 p = bp[k];
                    const float dx = p.x - hx, dy = p.y - hy, dz = p.z - hz;
                    best = fminf(best, fmaf(dx, dx, fmaf(dy, dy, dz * dz)));
                }
            }
        }

        // overflow list (normally empty), lane-strided
        const int on = *ocnt;
        for (int k = lane; k < on; k += 64) {
            const float4 p = ovf[k];
            if (__float_as_int(p.w) == b) {
                const float dx = p.x - hx, dy = p.y - hy, dz = p.z - hz;
                best = fminf(best, fmaf(dx, dx, fmaf(dy, dy, dz * dz)));
            }
        }

#pragma unroll
        for (int d = 1; d < 64; d <<= 1) best = fminf(best, __shfl_xor(best, d));

        // rare path: expanding shells, lane-strided over shell cells
        for (int r = 2; r < GRIDC; ++r) {
            const float bnd = (float)(r - 1) * CELL;
            if (best <= bnd * bnd) break;
            const int side = 2 * r + 1;
            const int ncells = side * side * side;
            for (int ci = lane; ci < ncells; ci += 64) {
                const int dx = ci % side - r;
                const int dy = (ci / side) % side - r;
                const int dz = ci / (side * side) - r;
                if (max(max(abs(dx), abs(dy)), abs(dz)) != r) continue; // shell only
                const int cx = hcx + dx, cy = hcy + dy, cz = hcz + dz;
                if (cx < 0 || cx >= GRIDC || cy < 0 || cy >= GRIDC ||
                    cz < 0 || cz >= GRIDC) continue;
                const int cell = cbase + (cz * GRIDC + cy) * GRIDC + cx;
                const int n = min(cnt[cell], CAP);
                const float4* bp = buckets + (size_t)cell * CAP;
                for (int k = 0; k < n; ++k) {
                    const float4 p = bp[k];
                    const float ddx = p.x - hx, ddy = p.y - hy, ddz = p.z - hz;
                    best = fminf(best, fmaf(ddx, ddx, fmaf(ddy, ddy, ddz * ddz)));
                }
            }
#pragma unroll
            for (int d = 1; d < 64; d <<= 1) best = fminf(best, __shfl_xor(best, d));
        }
    }

    // ---- fused stats: per-block LDS reduction + 5 relaxed shard atomics ----
    __shared__ double ssd[4], ssp[4], ssa[4];
    __shared__ int scp[4], sca[4];
    if (lane == 0) {
        double sd = 0.0, sp = 0.0, sa = 0.0;
        int cp = 0, ca = 0;
        if (valid) {
            const float d = sqrtf(fmaxf(best, 0.f));
            sd = (double)d;
            if (d < COLL) { const float t = COLL - d; sp = (double)(t * t); cp = 1; }
            const bool isc = (ql == 745) | (ql == 317) | (ql == 444) | (ql == 556) |
                             (ql == 673) | (ql == 95)  | (ql == 182) | (ql == 234) |
                             (ql == 279) | (ql == 320);
            if (isc & (d > COLL) & (d < CONT)) { sa = (double)(d * d); ca = 1; }
        }
        ssd[wave] = sd; ssp[wave] = sp; ssa[wave] = sa;
        scp[wave] = cp; sca[wave] = ca;
    }
    __syncthreads();
    if (tid == 0) {
        const double sd = ssd[0] + ssd[1] + ssd[2] + ssd[3];
        const double sp = ssp[0] + ssp[1] + ssp[2] + ssp[3];
        const double sa = ssa[0] + ssa[1] + ssa[2] + ssa[3];
        const int cp = scp[0] + scp[1] + scp[2] + scp[3];
        const int ca = sca[0] + sca[1] + sca[2] + sca[3];
        Shard* s = &shards[blockIdx.x & (NSH - 1)];
        atomicAdd(&s->sd, sd);
        atomicAdd(&s->sp, sp);
        atomicAdd(&s->sa, sa);
        atomicAdd(&s->cp, cp);
        atomicAdd(&s->ca, ca);
        // no fence, no ticket: next dispatch sees these (kernel boundary)
    }
}

// ---------------------------------------------------------------------------
// K3: 1-wave shard reduction -> 6 outputs (replaces 25-round 1-block finalize)
// ---------------------------------------------------------------------------
__global__ __launch_bounds__(64) void finalize_tiny(
    const Shard* __restrict__ shards, float* __restrict__ out, int nq)
{
    const int l = threadIdx.x;   // 64 threads, one shard each
    double sd = shards[l].sd, sp = shards[l].sp, sa = shards[l].sa;
    int cp = shards[l].cp, ca = shards[l].ca;
#pragma unroll
    for (int d = 1; d < 64; d <<= 1) {
        sd += __shfl_xor(sd, d);
        sp += __shfl_xor(sp, d);
        sa += __shfl_xor(sa, d);
        cp += __shfl_xor(cp, d);
        ca += __shfl_xor(ca, d);
    }
    if (l == 0) {
        const double pen_loss = cp > 0 ? sp / (double)cp : 0.0;
        const double att_loss = ca > 0 ? sa / (double)ca : 0.0;
        out[0] = (float)(100.0 * pen_loss + 10.0 * att_loss);
        out[1] = (float)pen_loss;
        out[2] = (float)att_loss;
        out[3] = (float)(sd / (double)nq);
        out[4] = (float)ca;
        out[5] = (float)cp;
    }
}

// ---------------------------------------------------------------------------
// Fallback brute-force (R10 kernel) if ws is too small for the grid. Writes
// uint bit-pattern mins of d2 — identical representation to plain float d2.
// ---------------------------------------------------------------------------
typedef float v2f __attribute__((ext_vector_type(2)));
constexpr int FT = 16, FG = 4, FBLK = 256, FCHUNK = 2560;
constexpr int FNBX = (NH + FG * FT - 1) / (FG * FT);
constexpr int FLPP = FCHUNK / FBLK, FPP = FLPP / 2;

__global__ __launch_bounds__(FBLK, 2) void nn_brute_kernel(
    const float* __restrict__ hand, const float* __restrict__ obj,
    unsigned int* __restrict__ minb, int V)
{
    __shared__ float s_red[4][16 * 65];
    const int bx = blockIdx.x, c = blockIdx.y, b = blockIdx.z;
    const int tid = threadIdx.x, wave = tid >> 6, lane = tid & 63;
    const int r = lane & 15, seg = lane >> 4;
    const float* ob = obj + (size_t)b * V * 3;
    const int base = c * FCHUNK + tid;
    v2f ox2[FPP], oy2[FPP], oz2[FPP], oq2[FPP];
#pragma unroll
    for (int p = 0; p < FPP; ++p) {
        const int ja = min(base + (2 * p + 0) * FBLK, V - 1);
        const int jb = min(base + (2 * p + 1) * FBLK, V - 1);
        const float xa = ob[3 * ja], ya = ob[3 * ja + 1], za = ob[3 * ja + 2];
        const float xb = ob[3 * jb], yb = ob[3 * jb + 1], zb = ob[3 * jb + 2];
        ox2[p] = (v2f){-2.f * xa, -2.f * xb};
        oy2[p] = (v2f){-2.f * ya, -2.f * yb};
        oz2[p] = (v2f){-2.f * za, -2.f * zb};
        oq2[p] = (v2f){fmaf(xa, xa, fmaf(ya, ya, za * za)),
                       fmaf(xb, xb, fmaf(yb, yb, zb * zb))};
    }
    const float* hb = hand + (size_t)b * NH * 3;
    float* sw = &s_red[wave][0];
#pragma unroll 1
    for (int g = 0; g < FG; ++g) {
        float hx[FT], hy[FT], hz[FT], m[FT];
#pragma unroll
        for (int t = 0; t < FT; ++t) {
            const int h = min((bx * FG + g) * FT + t, NH - 1);
            hx[t] = hb[3 * h]; hy[t] = hb[3 * h + 1]; hz[t] = hb[3 * h + 2];
            m[t] = 3.4e38f;
        }
#pragma unroll
        for (int p = 0; p < FPP; ++p) {
#pragma unroll
            for (int t = 0; t < FT; ++t) {
                v2f a = __builtin_elementwise_fma(ox2[p], (v2f){hx[t], hx[t]}, oq2[p]);
                a = __builtin_elementwise_fma(oy2[p], (v2f){hy[t], hy[t]}, a);
                a = __builtin_elementwise_fma(oz2[p], (v2f){hz[t], hz[t]}, a);
                m[t] = fminf(fminf(a.x, a.y), m[t]);
            }
        }
#pragma unroll
        for (int t = 0; t < FT; ++t) {
            const float hq = fmaf(hx[t], hx[t], fmaf(hy[t], hy[t], hz[t] * hz[t]));
            sw[t * 65 + lane] = m[t] + hq;
        }
        __builtin_amdgcn_wave_barrier();
        float v = 3.4e38f;
        const int rb = r * 65 + seg * 16;
#pragma unroll
        for (int j = 0; j < 16; ++j) v = fminf(v, sw[rb + j]);
        __builtin_amdgcn_wave_barrier();
        v = fminf(v, __shfl_xor(v, 16));
        v = fminf(v, __shfl_xor(v, 32));
        if (seg == 0) {
            const int hidx = (bx * FG + g) * FT + r;
            if (hidx < NH) {
                const unsigned bits = __float_as_uint(fmaxf(v, 0.f));
                unsigned int* p = &minb[b * NH + hidx];
                if (bits < *((volatile unsigned int*)p)) atomicMin(p, bits);
            }
        }
    }
}

// ---------------------------------------------------------------------------
// Final reduction for the FALLBACK path only (dist buffer holds d2 floats)
// ---------------------------------------------------------------------------
__global__ __launch_bounds__(256) void finalize_kernel(
    const float* __restrict__ dist, float* __restrict__ out, int B)
{
    constexpr float COLL = 0.005f;
    constexpr float CONT = 0.01f;
    const int total = B * NH;
    const int tid = threadIdx.x;

    double sum_d = 0.0, pen_sum = 0.0, att_sum = 0.0;
    int pen_cnt = 0, att_cnt = 0;
    for (int i = tid; i < total; i += 256) {
        const float d = sqrtf(fmaxf(dist[i], 0.f));
        sum_d += (double)d;
        if (d < COLL) { const float t = COLL - d; pen_sum += (double)(t * t); pen_cnt++; }
        const int n = i % NH;
        const bool isc = (n == 745) | (n == 317) | (n == 444) | (n == 556) |
                         (n == 673) | (n == 95)  | (n == 182) | (n == 234) |
                         (n == 279) | (n == 320);
        if (isc & (d > COLL) & (d < CONT)) { att_sum += (double)(d * d); att_cnt++; }
    }

    __shared__ double sd[256], sp[256], sa[256];
    __shared__ int    cp[256], ca[256];
    sd[tid] = sum_d; sp[tid] = pen_sum; sa[tid] = att_sum;
    cp[tid] = pen_cnt; ca[tid] = att_cnt;
    __syncthreads();
    for (int off = 128; off > 0; off >>= 1) {
        if (tid < off) {
            sd[tid] += sd[tid + off]; sp[tid] += sp[tid + off];
            sa[tid] += sa[tid + off];
            cp[tid] += cp[tid + off]; ca[tid] += ca[tid + off];
        }
        __syncthreads();
    }
    if (tid == 0) {
        const double pen_loss = cp[0] > 0 ? sp[0] / (double)cp[0] : 0.0;
        const double att_loss = ca[0] > 0 ? sa[0] / (double)ca[0] : 0.0;
        out[0] = (float)(100.0 * pen_loss + 10.0 * att_loss);
        out[1] = (float)pen_loss;
        out[2] = (float)att_loss;
        out[3] = (float)(sd[0] / (double)total);
        out[4] = (float)ca[0];
        out[5] = (float)cp[0];
    }
}

extern "C" void kernel_launch(void* const* d_in, const int* in_sizes, int n_in,
                              void* d_out, int out_size, void* d_ws, size_t ws_size,
                              hipStream_t stream) {
    const float* hand = (const float*)d_in[0];  // [B, 778, 3] fp32
    const float* obj  = (const float*)d_in[1];  // [B, V, 3]   fp32
    // d_in[2]/d_in[3] (faces): unused by the loss

    const int B = in_sizes[0] / (NH * 3);
    const int V = in_sizes[1] / (B * 3);
    const int total = B * V;
    const int nq = B * NH;

    // workspace layout: [0,64K) fallback dist | shards 4K | ocnt | cnt | buckets | ovf
    char* base = (char*)d_ws;
    size_t off = 65536;
    Shard* shards = (Shard*)(base + off);                         // 64*64B = 4KB
    int*   ocnt   = (int*)(base + off + 4096);                    // 1 int (64B slot)
    int*   cnt    = (int*)(base + off + 8192);                    // [B*NCELL]
    const size_t cnt_bytes = (size_t)B * NCELL * sizeof(int);
    const size_t boff = (off + 8192 + cnt_bytes + 255) & ~(size_t)255;
    float4* buckets = (float4*)(base + boff);                     // [B*NCELL*CAP]
    const size_t bkt_bytes = (size_t)B * NCELL * CAP * sizeof(float4);
    float4* ovf = (float4*)(base + boff + bkt_bytes);             // [B*V] worst case
    const size_t need = boff + bkt_bytes + (size_t)total * sizeof(float4);

    if (ws_size >= need) {
        // one fill zeroes shards + ocnt + cell counts (~136 KB)
        hipMemsetAsync(base + off, 0, 8192 + cnt_bytes, stream);

        // bin: 4 points/thread, 1024 points/block, XCD-affinity remap
        const int bpb = (V + 1023) / 1024;
        int gbin = B * bpb; gbin = (gbin + NXCD - 1) & ~(NXCD - 1);
        bin_kernel<<<gbin, 256, 0, stream>>>(obj, cnt, ocnt, buckets, ovf,
                                             B, V, bpb);

        // query: 1 wave/query, 4 queries/block, same batch->XCD mapping,
        // stats fused into padded shards
        const int bpq = (NH + 3) / 4;   // 195
        int gq = B * bpq; gq = (gq + NXCD - 1) & ~(NXCD - 1);
        query_kernel<<<gq, 256, 0, stream>>>(hand, cnt, buckets, ovf, ocnt,
                                             shards, B, bpq);

        finalize_tiny<<<1, 64, 0, stream>>>(shards, (float*)d_out, nq);
    } else {
        // brute-force fallback (uint bit-pattern mins == float d2)
        hipMemsetAsync(d_ws, 0x7F, (size_t)nq * sizeof(unsigned int), stream);
        dim3 grid(FNBX, (V + FCHUNK - 1) / FCHUNK, B);
        nn_brute_kernel<<<grid, FBLK, 0, stream>>>(hand, obj,
                                                   (unsigned int*)d_ws, V);
        finalize_kernel<<<1, 256, 0, stream>>>((const float*)d_ws, (float*)d_out, B);
    }
}